// Round 3
// baseline (413.301 us; speedup 1.0000x reference)
//
#include <hip/hip_runtime.h>

// DiscriminativeLoss — B=8, D=32, N=131072, K=64 bins.
// R3: ZERO global atomics. R2's flush was 2M device-scope fp32 atomics
// (WRITE_SIZE=8.4MB = 2M x 4B, all memory-side RMW) -> ~180us jam with every
// pipe idle. Now: per-block partials via plain stores + tiny reduction kernels.
//   k1: per-chunk cluster sums/counts -> part[b][ch][2112]
//   k2: reduce partials -> mu[b][k][d], cnt[b][k]
//   k3: hinged L1 variance vs mu      -> vpart[b][ch][64]
//   k4: single block: var reduce + pairwise + reg + final 4 outputs

#define IGNORE_IDX (-100)

constexpr int B = 8;
constexpr int D = 32;
constexpr int K = 64;
constexpr int CH = 64;                 // chunks per batch (2048 pts per block)
constexpr int CELLS = K * D + K;       // 2112: 2048 sums + 64 counts
constexpr float DELTA_V = 0.5f;
constexpr float TWO_DELTA_D = 3.0f;    // 2 * DELTA_D
constexpr float PARAM_REG = 0.001f;

// ws float layout:
//   part  : [B][CH][CELLS]  @ 0                (1,081,344 floats, 4.33 MB)
//   mu    : [B][K*D]        @ OFF_MU           (16,384)
//   cnt   : [B][K]          @ OFF_CNT          (512)
//   vpart : [B][CH][K]      @ OFF_VP           (32,768)
constexpr int OFF_MU  = B * CH * CELLS;
constexpr int OFF_CNT = OFF_MU + B * K * D;
constexpr int OFF_VP  = OFF_CNT + B * K;

// ---------------------------------------------------------------- K1: partial sums
__global__ __launch_bounds__(256) void k1_segsum(
    const float* __restrict__ x, const int* __restrict__ sem,
    const int* __restrict__ inst, float* __restrict__ part, int N)
{
    __shared__ float s_sums[K][D + 1];   // stride 33 -> bank (k+d)%32
    __shared__ int   s_counts[K];

    const int b     = blockIdx.x >> 6;       // CH = 64
    const int chunk = blockIdx.x & 63;
    const int t     = threadIdx.x;

    for (int i = t; i < K * (D + 1); i += 256) (&s_sums[0][0])[i] = 0.f;
    if (t < K) s_counts[t] = 0;
    __syncthreads();

    const float* xb = x + (size_t)b * D * N;

#pragma unroll
    for (int g = 0; g < 2; ++g) {            // 2048 pts/block, 1024 per group
        const int base = chunk * 2048 + g * 1024 + t * 4;
        const int4 c4 = *(const int4*)(sem  + (size_t)b * N + base);
        const int4 i4 = *(const int4*)(inst + (size_t)b * N + base);
        const int cl[4] = {c4.x, c4.y, c4.z, c4.w};
        const int il[4] = {i4.x, i4.y, i4.z, i4.w};
        int  id[4];
        bool v[4];
#pragma unroll
        for (int j = 0; j < 4; ++j) {
            v[j]  = (cl[j] != IGNORE_IDX);
            int q = (cl[j] == 1) ? 0 : il[j];
            id[j] = (q < 0) ? 0 : (q > K - 1 ? K - 1 : q);
        }
#pragma unroll
        for (int j = 0; j < 4; ++j)
            if (v[j]) atomicAdd(&s_counts[id[j]], 1);

#pragma unroll
        for (int dc = 0; dc < 4; ++dc) {
            float4 xv[8];
#pragma unroll
            for (int dd = 0; dd < 8; ++dd)
                xv[dd] = *(const float4*)(xb + (size_t)(dc * 8 + dd) * N + base);
#pragma unroll
            for (int dd = 0; dd < 8; ++dd) {
                const int d = dc * 8 + dd;
                if (v[0]) unsafeAtomicAdd(&s_sums[id[0]][d], xv[dd].x);
                if (v[1]) unsafeAtomicAdd(&s_sums[id[1]][d], xv[dd].y);
                if (v[2]) unsafeAtomicAdd(&s_sums[id[2]][d], xv[dd].z);
                if (v[3]) unsafeAtomicAdd(&s_sums[id[3]][d], xv[dd].w);
            }
        }
    }
    __syncthreads();

    // plain coalesced flush of the full partial slice
    float* slice = part + ((size_t)b * CH + chunk) * CELLS;
    for (int i = t; i < K * D; i += 256) slice[i] = s_sums[i >> 5][i & 31];
    if (t < K) slice[K * D + t] = (float)s_counts[t];
}

// ---------------------------------------------------------------- K2: reduce -> mu, cnt
__global__ __launch_bounds__(256) void k2_mu(const float* __restrict__ part,
                                             float* __restrict__ mu,
                                             float* __restrict__ cnt)
{
    const int gid  = blockIdx.x * 256 + threadIdx.x;   // exactly B*CELLS = 16896
    const int b    = gid / CELLS;
    const int cell = gid - b * CELLS;
    const float* pb = part + (size_t)b * CH * CELLS;

    if (cell < K * D) {
        const int k = cell >> 5;
        float s = 0.f, c = 0.f;
        for (int ch = 0; ch < CH; ++ch) {
            s += pb[(size_t)ch * CELLS + cell];
            c += pb[(size_t)ch * CELLS + K * D + k];
        }
        mu[b * K * D + cell] = s / (c + 1e-8f);
    } else {
        const int k = cell - K * D;
        float c = 0.f;
        for (int ch = 0; ch < CH; ++ch) c += pb[(size_t)ch * CELLS + K * D + k];
        cnt[b * K + k] = c;
    }
}

// ---------------------------------------------------------------- K3: variance pass
__global__ __launch_bounds__(256) void k3_var(
    const float* __restrict__ x, const int* __restrict__ sem,
    const int* __restrict__ inst, const float* __restrict__ mu,
    float* __restrict__ vpart, int N)
{
    __shared__ float s_mu[K][D + 1];
    __shared__ float s_var[K];

    const int b     = blockIdx.x >> 6;
    const int chunk = blockIdx.x & 63;
    const int t     = threadIdx.x;

    for (int i = t; i < K * D; i += 256) s_mu[i >> 5][i & 31] = mu[b * K * D + i];
    if (t < K) s_var[t] = 0.f;
    __syncthreads();

    const float* xb = x + (size_t)b * D * N;

#pragma unroll
    for (int g = 0; g < 2; ++g) {
        const int base = chunk * 2048 + g * 1024 + t * 4;
        const int4 c4 = *(const int4*)(sem  + (size_t)b * N + base);
        const int4 i4 = *(const int4*)(inst + (size_t)b * N + base);
        const int cl[4] = {c4.x, c4.y, c4.z, c4.w};
        const int il[4] = {i4.x, i4.y, i4.z, i4.w};
        int  id[4];
        bool v[4];
#pragma unroll
        for (int j = 0; j < 4; ++j) {
            v[j]  = (cl[j] != IGNORE_IDX);
            int q = (cl[j] == 1) ? 0 : il[j];
            id[j] = (q < 0) ? 0 : (q > K - 1 ? K - 1 : q);
        }
        float dist[4] = {0.f, 0.f, 0.f, 0.f};
#pragma unroll
        for (int dc = 0; dc < 4; ++dc) {
            float4 xv[8];
#pragma unroll
            for (int dd = 0; dd < 8; ++dd)
                xv[dd] = *(const float4*)(xb + (size_t)(dc * 8 + dd) * N + base);
#pragma unroll
            for (int dd = 0; dd < 8; ++dd) {
                const int d = dc * 8 + dd;
                dist[0] += fabsf(xv[dd].x - s_mu[id[0]][d]);
                dist[1] += fabsf(xv[dd].y - s_mu[id[1]][d]);
                dist[2] += fabsf(xv[dd].z - s_mu[id[2]][d]);
                dist[3] += fabsf(xv[dd].w - s_mu[id[3]][d]);
            }
        }
#pragma unroll
        for (int j = 0; j < 4; ++j) {
            if (v[j]) {
                const float h = fmaxf(dist[j] - DELTA_V, 0.f);
                if (h > 0.f) unsafeAtomicAdd(&s_var[id[j]], h * h);
            }
        }
    }
    __syncthreads();

    if (t < K) vpart[((size_t)b * CH + chunk) * K + t] = s_var[t];
}

// ---------------------------------------------------------------- K4: finalize (1 block)
__device__ float block_reduce_sum512(float v, float* s_buf) {
    for (int o = 32; o > 0; o >>= 1) v += __shfl_down(v, o, 64);
    const int wid  = threadIdx.x >> 6;
    const int lane = threadIdx.x & 63;
    if (lane == 0) s_buf[wid] = v;
    __syncthreads();
    float r = 0.f;
    if (threadIdx.x == 0)
        for (int w = 0; w < 8; ++w) r += s_buf[w];
    __syncthreads();
    return r;   // valid on thread 0 only
}

__global__ __launch_bounds__(512) void k4_final(const float* __restrict__ mu,
                                                const float* __restrict__ cnt,
                                                const float* __restrict__ vpart,
                                                float* __restrict__ out)
{
    __shared__ float s_mu[K][D + 1];
    __shared__ float s_cnt[B * K];      // 512
    __shared__ float s_varseg[B * K];   // per-(b,k) normalized var
    __shared__ float s_red[8];

    const int t = threadIdx.x;

    s_cnt[t] = cnt[t];                  // 512 == B*K exactly
    __syncthreads();

    {   // var partial reduce: thread t owns (b = t>>6, k = t&63)
        const int b = t >> 6, k = t & 63;
        float vs = 0.f;
        for (int ch = 0; ch < CH; ++ch)
            vs += vpart[((size_t)b * CH + ch) * K + k];
        s_varseg[t] = vs / (s_cnt[t] + 1e-8f);
    }
    __syncthreads();

    float acc_loss = 0.f, acc_var = 0.f, acc_dist = 0.f, acc_reg = 0.f;

    for (int b = 0; b < B; ++b) {
        for (int i = t; i < K * D; i += 512) s_mu[i >> 5][i & 31] = mu[b * K * D + i];
        __syncthreads();

        float distPart = 0.f;
        for (int p = t; p < K * K; p += 512) {
            const int i = p >> 6, j = p & 63;
            if (i != j && s_cnt[b * K + i] > 0.f && s_cnt[b * K + j] > 0.f) {
                float dsum = 0.f;
#pragma unroll
                for (int d = 0; d < D; ++d) dsum += fabsf(s_mu[i][d] - s_mu[j][d]);
                const float h = fmaxf(TWO_DELTA_D - dsum, 0.f);
                distPart += h * h;
            }
        }
        float regPart = 0.f;
        for (int i = t; i < K * D; i += 512) {
            const int k = i >> 5;
            if (s_cnt[b * K + k] > 0.f) regPart += fabsf(s_mu[k][i & 31]);
        }

        const float distSum = block_reduce_sum512(distPart, s_red);
        const float regSum  = block_reduce_sum512(regPart,  s_red);

        if (t == 0) {
            float np = 0.f, varSum = 0.f;
            for (int k = 0; k < K; ++k) {
                np     += (s_cnt[b * K + k] > 0.f) ? 1.f : 0.f;
                varSum += s_varseg[b * K + k];
            }
            const float n_inst = fmaxf(np, 1.0f);
            const float npairs = np * np - np;
            const float l_var  = varSum / n_inst;
            const float l_dist = (npairs > 0.f) ? (distSum / fmaxf(npairs, 1.0f)) : 0.f;
            const float l_reg  = PARAM_REG * (regSum / n_inst);
            acc_loss += l_var + l_dist + l_reg;
            acc_var  += l_var;
            acc_dist += l_dist;
            acc_reg  += l_reg;
        }
        __syncthreads();   // protect s_mu reload next iteration
    }

    if (t == 0) {
        const float invB = 1.0f / (float)B;
        out[0] = acc_loss * invB;
        out[1] = acc_var  * invB;
        out[2] = acc_dist * invB;
        out[3] = acc_reg  * invB;
    }
}

// ---------------------------------------------------------------- launch
extern "C" void kernel_launch(void* const* d_in, const int* in_sizes, int n_in,
                              void* d_out, int out_size, void* d_ws, size_t ws_size,
                              hipStream_t stream) {
    const float* x    = (const float*)d_in[0];
    const int*   sem  = (const int*)d_in[1];
    const int*   inst = (const int*)d_in[2];
    float*       out  = (float*)d_out;
    float*       ws   = (float*)d_ws;

    float* part  = ws;
    float* mu    = ws + OFF_MU;
    float* cnt   = ws + OFF_CNT;
    float* vpart = ws + OFF_VP;

    const int N = in_sizes[1] / B;

    k1_segsum<<<dim3(B * CH), dim3(256), 0, stream>>>(x, sem, inst, part, N);
    k2_mu<<<dim3(B * CELLS / 256), dim3(256), 0, stream>>>(part, mu, cnt);
    k3_var<<<dim3(B * CH), dim3(256), 0, stream>>>(x, sem, inst, mu, vpart, N);
    k4_final<<<dim3(1), dim3(512), 0, stream>>>(mu, cnt, vpart, out);
}